// Round 9
// baseline (160.132 us; speedup 1.0000x reference)
//
#include <hip/hip_runtime.h>
#include <stdint.h>

typedef __attribute__((ext_vector_type(8))) short bf16x8;
typedef __attribute__((ext_vector_type(4))) float f32x4;

__device__ __forceinline__ uint32_t f2bf(float f) {
    uint32_t u = __builtin_bit_cast(uint32_t, f);
    u += 0x7fffu + ((u >> 16) & 1u);   // RNE round to bf16
    return u >> 16;
}
__device__ __forceinline__ uint32_t pack2(float a, float b) {
    return f2bf(a) | (f2bf(b) << 16);
}

// Prep 1: reciprocal norms 1/max(||row||, eps).
__global__ __launch_bounds__(256) void prep_norms(const float* __restrict__ qe,
                                                  const float* __restrict__ pe,
                                                  float* __restrict__ rq,
                                                  float* __restrict__ rp,
                                                  int Q, int Pn) {
    int gw = (blockIdx.x * 256 + threadIdx.x) >> 6;  // one wave per row
    int lane = threadIdx.x & 63;
    if (gw >= Q + Pn) return;
    const float* src = (gw < Q) ? (qe + (size_t)gw * 128) : (pe + (size_t)(gw - Q) * 128);
    float2 v = *(const float2*)(src + lane * 2);
    float s = v.x * v.x + v.y * v.y;
#pragma unroll
    for (int off = 32; off > 0; off >>= 1) s += __shfl_down(s, off, 64);
    if (lane == 0) {
        float r = 1.0f / fmaxf(sqrtf(s), 1e-8f);
        if (gw < Q) rq[gw] = r; else rp[gw - Q] = r;
    }
}

// Prep 2: fp32 [rows][128] -> bf16 in MFMA-fragment order.
// Fragment (g = 16-row group, c = 32-wide k chunk): lane holds row g*16+(lane&15),
// k = c*32+(lane>>4)*8 .. +7. Flat halfword offset = ((g*4+c)*64 + lane)*8.
// A wave's fragment load in the GEMM = 64 contiguous 16B chunks = 1KB coalesced.
__global__ __launch_bounds__(256) void conv_frag(const float* __restrict__ src,
                                                 unsigned short* __restrict__ dst,
                                                 int ngroups) {
    int t = blockIdx.x * 256 + threadIdx.x;   // one thread per 8 outputs
    if (t >= ngroups * 256) return;
    int g = t >> 8, rem = t & 255;
    int c = rem >> 6, lane = rem & 63;
    int row = g * 16 + (lane & 15);
    int col = c * 32 + ((lane >> 4) << 3);
    const float* s = src + (size_t)row * 128 + col;
    float4 a0 = *(const float4*)s;
    float4 a1 = *(const float4*)(s + 4);
    uint4 pk = { pack2(a0.x, a0.y), pack2(a0.z, a0.w),
                 pack2(a1.x, a1.y), pack2(a1.z, a1.w) };
    *(uint4*)(dst + (size_t)t * 8) = pk;
}

// xor matrix = (qid[q]==pid[p]): expected density ~1/30000 -> memset-0 (async,
// fill-speed) + sparse scatter of the ~2200 ones. pid (64KB) is L2-hot.
__global__ __launch_bounds__(256) void xor_scatter(const int* __restrict__ qid,
                                                   const int* __restrict__ pid,
                                                   float* __restrict__ oxor,
                                                   int Q, int Pn) {
    int T = blockIdx.x * 256 + threadIdx.x;   // 64 threads per q-row
    int q = T >> 6;
    if (q >= Q) return;
    const int qv = qid[q];
    const int stripe = Pn >> 6;               // 256
    const int p0 = (T & 63) * stripe;
    const size_t base = (size_t)q * Pn;
    const int4* pp = (const int4*)(pid + p0);
#pragma unroll 4
    for (int i = 0; i < 64; ++i) {            // 256 ints = 64 x int4
        int4 pv = pp[i];
        int p = p0 + i * 4;
        if (pv.x == qv) oxor[base + p]     = 1.f;
        if (pv.y == qv) oxor[base + p + 1] = 1.f;
        if (pv.z == qv) oxor[base + p + 2] = 1.f;
        if (pv.w == qv) oxor[base + p + 3] = 1.f;
    }
}

#define PBLK 8192   // p extent per block (half of P)

// cos-only GEMM v9: ZERO barriers. Block = 16q x 8192p, 4 waves; per round each
// wave owns a contiguous 256p span. Wave-private LDS transpose (stride 260 words:
// min-phase bank pattern on both b128 write and read). Flush = 16 rows x 1KB
// contiguous dwordx4 stores (fill-identical width), normal stores like the fill.
// 512 blocks = 2/CU, all resident; every wave an independent stream.
__global__ __launch_bounds__(256, 2) void cos_gemm(
        const unsigned short* __restrict__ Qf, const unsigned short* __restrict__ Pf,
        const float* __restrict__ rq, const float* __restrict__ rp,
        float* __restrict__ ocos, int Pn) {
    __shared__ __align__(16) float scos[4][16][260];   // 65KB, per-wave slices

    // Bijective XCD chunking, pc-major: each XCD chunk = 64 consecutive q-groups
    // x one 8192p half -> per-XCD L2 set = 2MB Pf-half + 256KB Qf slice.
    const int nwg = gridDim.x;                 // 512
    const int chunk = nwg >> 3;                // 64
    const int bid = blockIdx.x;
    const int wg = (bid & 7) * chunk + (bid >> 3);
    const int qg = wg & 255;
    const int pc = wg >> 8;
    const int pblock = pc * PBLK;

    const int t = threadIdx.x;
    const int lane = t & 63;
    const int w = t >> 6;
    const int lq = lane & 15;
    const int g4 = (lane >> 4) << 2;   // 0,4,8,12

    // A fragments: coalesced 1KB loads, shared by all 4 waves
    bf16x8 af[4];
    const unsigned short* abase = Qf + (size_t)qg * 2048 + lane * 8;
#pragma unroll
    for (int kk = 0; kk < 4; ++kk)
        af[kk] = *(const bf16x8*)(abase + kk * 512);

    const int qrow_base = qg * 16;
    const float rqv = rq[qrow_base + lq];

    for (int fl = 0; fl < PBLK / 1024; ++fl) {
        const int pw = pblock + fl * 1024 + w * 256;   // wave's 256p span
        // ---- compute: 16 fragments, deposit scaled cos into private slice ----
#pragma unroll 4
        for (int f = 0; f < 16; ++f) {
            const int p0 = pw + f * 16;
            const unsigned short* bbase = Pf + (size_t)(p0 >> 4) * 2048 + (size_t)lane * 8;
            bf16x8 bfr[4];
#pragma unroll
            for (int kk = 0; kk < 4; ++kk)
                bfr[kk] = *(const bf16x8*)(bbase + kk * 512);
            f32x4 acc = {0.f, 0.f, 0.f, 0.f};
#pragma unroll
            for (int kk = 0; kk < 4; ++kk)
                acc = __builtin_amdgcn_mfma_f32_16x16x32_bf16(bfr[kk], af[kk], acc, 0, 0, 0);
            // C layout: lane holds q = lane&15, p = p0 + (lane>>4)*4 + reg
            const float4 rpv = *(const float4*)(rp + p0 + g4);
            f32x4 c4 = { acc[0]*rqv*rpv.x, acc[1]*rqv*rpv.y,
                         acc[2]*rqv*rpv.z, acc[3]*rqv*rpv.w };
            *(f32x4*)&scos[w][lq][f * 16 + g4] = c4;
        }
        // ---- flush (same wave, no barrier): 16 rows x 1KB contiguous ----
#pragma unroll
        for (int r = 0; r < 16; ++r) {
            f32x4 vc = *(const f32x4*)&scos[w][r][lane * 4];
            *(f32x4*)(ocos + (size_t)(qrow_base + r) * Pn + pw + lane * 4) = vc;
        }
    }
}

extern "C" void kernel_launch(void* const* d_in, const int* in_sizes, int n_in,
                              void* d_out, int out_size, void* d_ws, size_t ws_size,
                              hipStream_t stream) {
    const int*   qid = (const int*)d_in[0];
    const int*   pid = (const int*)d_in[1];
    const float* qe  = (const float*)d_in[2];
    const float* pe  = (const float*)d_in[3];
    const int Q  = in_sizes[0];   // 4096
    const int Pn = in_sizes[1];   // 16384

    // ws layout: Qf bf16 (Q*128), Pf bf16 (P*128), rq (Q), rp (P)  ~= 5.3 MB
    unsigned short* Qf = (unsigned short*)d_ws;
    unsigned short* Pf = Qf + (size_t)Q * 128;
    float* rq = (float*)(Pf + (size_t)Pn * 128);
    float* rp = rq + Q;

    float* oxor = (float*)d_out;
    float* ocos = oxor + (size_t)Q * (size_t)Pn;

    // xor output: fill-speed memset + sparse scatter (runs while nothing else can
    // overlap, but at pure-fill BW)
    hipMemsetAsync(oxor, 0, (size_t)Q * (size_t)Pn * sizeof(float), stream);

    const int qgroups = Q / 16, pgroups = Pn / 16;
    conv_frag<<<qgroups, 256, 0, stream>>>(qe, Qf, qgroups);
    conv_frag<<<pgroups, 256, 0, stream>>>(pe, Pf, pgroups);
    prep_norms<<<(Q + Pn + 3) / 4, 256, 0, stream>>>(qe, pe, rq, rp, Q, Pn);

    xor_scatter<<<(Q * 64) / 256, 256, 0, stream>>>(qid, pid, oxor, Q, Pn);

    const int nblocks = (Q / 16) * (Pn / PBLK);   // 256 * 2 = 512
    cos_gemm<<<nblocks, 256, 0, stream>>>(Qf, Pf, rq, rp, ocos, Pn);
}

// Round 10
// 138.884 us; speedup vs baseline: 1.1530x; 1.1530x over previous
//
#include <hip/hip_runtime.h>
#include <stdint.h>

typedef __attribute__((ext_vector_type(8))) short bf16x8;
typedef __attribute__((ext_vector_type(4))) float f32x4;

__device__ __forceinline__ uint32_t f2bf(float f) {
    uint32_t u = __builtin_bit_cast(uint32_t, f);
    u += 0x7fffu + ((u >> 16) & 1u);   // RNE round to bf16
    return u >> 16;
}
__device__ __forceinline__ uint32_t pack2(float a, float b) {
    return f2bf(a) | (f2bf(b) << 16);
}

// Prep 1: reciprocal norms 1/max(||row||, eps).
__global__ __launch_bounds__(256) void prep_norms(const float* __restrict__ qe,
                                                  const float* __restrict__ pe,
                                                  float* __restrict__ rq,
                                                  float* __restrict__ rp,
                                                  int Q, int Pn) {
    int gw = (blockIdx.x * 256 + threadIdx.x) >> 6;  // one wave per row
    int lane = threadIdx.x & 63;
    if (gw >= Q + Pn) return;
    const float* src = (gw < Q) ? (qe + (size_t)gw * 128) : (pe + (size_t)(gw - Q) * 128);
    float2 v = *(const float2*)(src + lane * 2);
    float s = v.x * v.x + v.y * v.y;
#pragma unroll
    for (int off = 32; off > 0; off >>= 1) s += __shfl_down(s, off, 64);
    if (lane == 0) {
        float r = 1.0f / fmaxf(sqrtf(s), 1e-8f);
        if (gw < Q) rq[gw] = r; else rp[gw - Q] = r;
    }
}

// Prep 2: fp32 [rows][128] -> bf16 in MFMA-fragment order.
// Fragment (g = 16-row group, c = 32-wide k chunk): lane holds row g*16+(lane&15),
// k = c*32+(lane>>4)*8 .. +7. Flat halfword offset = ((g*4+c)*64 + lane)*8.
// A wave's fragment load in the GEMM = 64 contiguous 16B chunks = 1KB coalesced.
__global__ __launch_bounds__(256) void conv_frag(const float* __restrict__ src,
                                                 unsigned short* __restrict__ dst,
                                                 int ngroups) {
    int t = blockIdx.x * 256 + threadIdx.x;   // one thread per 8 outputs
    if (t >= ngroups * 256) return;
    int g = t >> 8, rem = t & 255;
    int c = rem >> 6, lane = rem & 63;
    int row = g * 16 + (lane & 15);
    int col = c * 32 + ((lane >> 4) << 3);
    const float* s = src + (size_t)row * 128 + col;
    float4 a0 = *(const float4*)s;
    float4 a1 = *(const float4*)(s + 4);
    uint4 pk = { pack2(a0.x, a0.y), pack2(a0.z, a0.w),
                 pack2(a1.x, a1.y), pack2(a1.z, a1.w) };
    *(uint4*)(dst + (size_t)t * 8) = pk;
}

#define PBLK 2048   // p extent per block

// Main v10: R8 structure (ZERO barriers, wave-private 16x64p LDS transpose,
// fused xor) with register pressure squeezed to <=64 VGPR so 8 waves/SIMD
// (32 waves/CU, 8 blocks/CU) are resident: 2x the latency-hiding of R8.
// All B-frag/flush addresses are 32-bit offsets from uniform bases (saddr form).
__global__ __launch_bounds__(256, 8) void fused_gemm(
        const unsigned short* __restrict__ Qf, const unsigned short* __restrict__ Pf,
        const int* __restrict__ qid, const int* __restrict__ pid,
        const float* __restrict__ rq, const float* __restrict__ rp,
        float* __restrict__ oxor, float* __restrict__ ocos, int Pn) {
    __shared__ __align__(16) float scos[4 * 16 * 65];   // 16.6KB, per-wave slices

    // Bijective XCD chunking: XCD x owns a contiguous run of row-panels.
    const int nwg = gridDim.x;
    const int chunk = nwg >> 3;
    const int bid = blockIdx.x;
    const int wg = (bid & 7) * chunk + (bid >> 3);
    const int nPc = Pn / PBLK;
    const int qg = wg / nPc;           // 16-row q group
    const int pc = wg % nPc;
    const int pblock = pc * PBLK;

    const int t = threadIdx.x;
    const int lane = t & 63;
    const int w = t >> 6;
    const int lq = lane & 15;
    const int g4 = (lane >> 4) << 2;   // 0,4,8,12
    const int wbase = w * (16 * 65);   // wave-private LDS slice (words)

    // A fragments: coalesced 1KB loads, shared rows for all waves (16 VGPR)
    bf16x8 af[4];
    {
        const uint32_t aoff = (uint32_t)(qg * 2048 + lane * 8);
#pragma unroll
        for (int kk = 0; kk < 4; ++kk)
            af[kk] = *(const bf16x8*)(Qf + aoff + kk * 512);
    }

    const int qrow_base = qg * 16;
    const float rqv = rq[qrow_base + lq];

    for (int fl = 0; fl < PBLK / 256; ++fl) {
        const int pw = pblock + fl * 256 + w * 64;   // this wave's 64p span
        // ---- compute: 4 fragments = 64p; consume each B-frag immediately ----
#pragma unroll
        for (int f = 0; f < 4; ++f) {
            const int p0 = pw + f * 16;
            const uint32_t boff = (uint32_t)((p0 >> 4) * 2048 + lane * 8);
            f32x4 acc = {0.f, 0.f, 0.f, 0.f};
#pragma unroll
            for (int kk = 0; kk < 4; ++kk) {
                bf16x8 bfr = *(const bf16x8*)(Pf + boff + kk * 512);
                acc = __builtin_amdgcn_mfma_f32_16x16x32_bf16(bfr, af[kk], acc, 0, 0, 0);
            }
            // C layout: lane holds q = lane&15, p = p0 + (lane>>4)*4 + reg
            const float4 rpv = *(const float4*)(rp + p0 + g4);
            const int a0 = wbase + lq * 65 + f * 16 + g4;
            scos[a0 + 0] = acc[0] * rqv * rpv.x;
            scos[a0 + 1] = acc[1] * rqv * rpv.y;
            scos[a0 + 2] = acc[2] * rqv * rpv.z;
            scos[a0 + 3] = acc[3] * rqv * rpv.w;
        }
        // ---- flush (same wave, no barrier): 16 rows x 256B contiguous ----
        const int pvl = pid[pw + lane];
#pragma unroll
        for (int r = 0; r < 16; ++r) {
            const int qvr = qid[qrow_base + r];            // wave-uniform
            const size_t obase = (size_t)(qrow_base + r) * Pn + pw;
            float vc = scos[wbase + r * 65 + lane];
            float vx = (qvr == pvl) ? 1.f : 0.f;
            __builtin_nontemporal_store(vc, ocos + obase + lane);
            __builtin_nontemporal_store(vx, oxor + obase + lane);
        }
    }
}

extern "C" void kernel_launch(void* const* d_in, const int* in_sizes, int n_in,
                              void* d_out, int out_size, void* d_ws, size_t ws_size,
                              hipStream_t stream) {
    const int*   qid = (const int*)d_in[0];
    const int*   pid = (const int*)d_in[1];
    const float* qe  = (const float*)d_in[2];
    const float* pe  = (const float*)d_in[3];
    const int Q  = in_sizes[0];   // 4096
    const int Pn = in_sizes[1];   // 16384

    // ws layout: Qf bf16 (Q*128), Pf bf16 (P*128), rq (Q), rp (P)  ~= 5.3 MB
    unsigned short* Qf = (unsigned short*)d_ws;
    unsigned short* Pf = Qf + (size_t)Q * 128;
    float* rq = (float*)(Pf + (size_t)Pn * 128);
    float* rp = rq + Q;

    float* oxor = (float*)d_out;
    float* ocos = oxor + (size_t)Q * (size_t)Pn;

    const int qgroups = Q / 16, pgroups = Pn / 16;
    conv_frag<<<qgroups, 256, 0, stream>>>(qe, Qf, qgroups);
    conv_frag<<<pgroups, 256, 0, stream>>>(pe, Pf, pgroups);
    prep_norms<<<(Q + Pn + 3) / 4, 256, 0, stream>>>(qe, pe, rq, rp, Q, Pn);

    const int nblocks = (Q / 16) * (Pn / PBLK);   // 256 * 8 = 2048
    fused_gemm<<<nblocks, 256, 0, stream>>>(Qf, Pf, qid, pid, rq, rp, oxor, ocos, Pn);
}

// Round 11
// 138.003 us; speedup vs baseline: 1.1603x; 1.0064x over previous
//
#include <hip/hip_runtime.h>
#include <stdint.h>

typedef __attribute__((ext_vector_type(8))) short bf16x8;
typedef __attribute__((ext_vector_type(4))) float f32x4;

__device__ __forceinline__ uint32_t f2bf(float f) {
    uint32_t u = __builtin_bit_cast(uint32_t, f);
    u += 0x7fffu + ((u >> 16) & 1u);   // RNE round to bf16
    return u >> 16;
}
__device__ __forceinline__ uint32_t pack2(float a, float b) {
    return f2bf(a) | (f2bf(b) << 16);
}

// Prep 1: reciprocal norms 1/max(||row||, eps).
__global__ __launch_bounds__(256) void prep_norms(const float* __restrict__ qe,
                                                  const float* __restrict__ pe,
                                                  float* __restrict__ rq,
                                                  float* __restrict__ rp,
                                                  int Q, int Pn) {
    int gw = (blockIdx.x * 256 + threadIdx.x) >> 6;  // one wave per row
    int lane = threadIdx.x & 63;
    if (gw >= Q + Pn) return;
    const float* src = (gw < Q) ? (qe + (size_t)gw * 128) : (pe + (size_t)(gw - Q) * 128);
    float2 v = *(const float2*)(src + lane * 2);
    float s = v.x * v.x + v.y * v.y;
#pragma unroll
    for (int off = 32; off > 0; off >>= 1) s += __shfl_down(s, off, 64);
    if (lane == 0) {
        float r = 1.0f / fmaxf(sqrtf(s), 1e-8f);
        if (gw < Q) rq[gw] = r; else rp[gw - Q] = r;
    }
}

// Prep 2: fp32 [rows][128] -> bf16 in MFMA-fragment order.
// Fragment (g = 16-row group, c = 32-wide k chunk): lane holds row g*16+(lane&15),
// k = c*32+(lane>>4)*8 .. +7. Flat halfword offset = ((g*4+c)*64 + lane)*8.
// A wave's fragment load in the GEMM = 64 contiguous 16B chunks = 1KB coalesced.
__global__ __launch_bounds__(256) void conv_frag(const float* __restrict__ src,
                                                 unsigned short* __restrict__ dst,
                                                 int ngroups) {
    int t = blockIdx.x * 256 + threadIdx.x;   // one thread per 8 outputs
    if (t >= ngroups * 256) return;
    int g = t >> 8, rem = t & 255;
    int c = rem >> 6, lane = rem & 63;
    int row = g * 16 + (lane & 15);
    int col = c * 32 + ((lane >> 4) << 3);
    const float* s = src + (size_t)row * 128 + col;
    float4 a0 = *(const float4*)s;
    float4 a1 = *(const float4*)(s + 4);
    uint4 pk = { pack2(a0.x, a0.y), pack2(a0.z, a0.w),
                 pack2(a1.x, a1.y), pack2(a1.z, a1.w) };
    *(uint4*)(dst + (size_t)t * 8) = pk;
}

#define PBLK 2048   // p extent per block

// Main v11 = R8 EXACTLY, except: plain stores instead of nontemporal (A/B on the
// NT-store theory). ZERO barriers, wave-private 16x64p LDS transpose, fused xor.
__global__ __launch_bounds__(256, 4) void fused_gemm(
        const unsigned short* __restrict__ Qf, const unsigned short* __restrict__ Pf,
        const int* __restrict__ qid, const int* __restrict__ pid,
        const float* __restrict__ rq, const float* __restrict__ rp,
        float* __restrict__ oxor, float* __restrict__ ocos, int Pn) {
    __shared__ __align__(16) float scos[4 * 16 * 65];   // 16.6KB, per-wave slices

    // Bijective XCD chunking: XCD x owns a contiguous run of row-panels ->
    // contiguous ~64MB output slab per XCD; Qf slice stays L2-hot.
    const int nwg = gridDim.x;
    const int chunk = nwg >> 3;
    const int bid = blockIdx.x;
    const int wg = (bid & 7) * chunk + (bid >> 3);
    const int nPc = Pn / PBLK;
    const int qg = wg / nPc;           // 16-row q group
    const int pc = wg % nPc;
    const int pblock = pc * PBLK;

    const int t = threadIdx.x;
    const int lane = t & 63;
    const int w = t >> 6;
    const int lq = lane & 15;
    const int g4 = (lane >> 4) << 2;   // 0,4,8,12
    const int wbase = w * (16 * 65);   // this wave's private LDS slice (words)

    // A fragments (shared rows for all waves): coalesced 1KB loads
    bf16x8 af[4];
    const unsigned short* abase = Qf + ((size_t)(qg * 4) * 64 + lane) * 8;
#pragma unroll
    for (int kk = 0; kk < 4; ++kk)
        af[kk] = *(const bf16x8*)(abase + kk * 512);

    const int qrow_base = qg * 16;
    const float rqv = rq[qrow_base + lq];

    for (int fl = 0; fl < PBLK / 256; ++fl) {
        const int pw = pblock + fl * 256 + w * 64;   // this wave's 64p span
        // ---- compute: 4 fragments = 64p, deposit scaled cos into private slice ----
#pragma unroll
        for (int f = 0; f < 4; ++f) {
            const int p0 = pw + f * 16;
            const unsigned short* bbase = Pf + (size_t)(p0 >> 4) * 2048 + (size_t)lane * 8;
            bf16x8 bfr[4];
#pragma unroll
            for (int kk = 0; kk < 4; ++kk)
                bfr[kk] = *(const bf16x8*)(bbase + kk * 512);
            f32x4 acc = {0.f, 0.f, 0.f, 0.f};
#pragma unroll
            for (int kk = 0; kk < 4; ++kk)
                acc = __builtin_amdgcn_mfma_f32_16x16x32_bf16(bfr[kk], af[kk], acc, 0, 0, 0);
            // C layout: lane holds q = lane&15, p = p0 + (lane>>4)*4 + reg
            const float4 rpv = *(const float4*)(rp + p0 + g4);
            const int a0 = wbase + lq * 65 + f * 16 + g4;
            scos[a0 + 0] = acc[0] * rqv * rpv.x;
            scos[a0 + 1] = acc[1] * rqv * rpv.y;
            scos[a0 + 2] = acc[2] * rqv * rpv.z;
            scos[a0 + 3] = acc[3] * rqv * rpv.w;
        }
        // ---- flush (same wave, no barrier): 16 rows x 256B contiguous ----
        const int pvl = pid[pw + lane];
#pragma unroll
        for (int r = 0; r < 16; ++r) {
            const int qvr = qid[qrow_base + r];            // wave-uniform
            const size_t obase = (size_t)(qrow_base + r) * Pn + pw;
            float vc = scos[wbase + r * 65 + lane];
            float vx = (qvr == pvl) ? 1.f : 0.f;
            ocos[obase + lane] = vc;
            oxor[obase + lane] = vx;
        }
    }
}

extern "C" void kernel_launch(void* const* d_in, const int* in_sizes, int n_in,
                              void* d_out, int out_size, void* d_ws, size_t ws_size,
                              hipStream_t stream) {
    const int*   qid = (const int*)d_in[0];
    const int*   pid = (const int*)d_in[1];
    const float* qe  = (const float*)d_in[2];
    const float* pe  = (const float*)d_in[3];
    const int Q  = in_sizes[0];   // 4096
    const int Pn = in_sizes[1];   // 16384

    // ws layout: Qf bf16 (Q*128), Pf bf16 (P*128), rq (Q), rp (P)  ~= 5.3 MB
    unsigned short* Qf = (unsigned short*)d_ws;
    unsigned short* Pf = Qf + (size_t)Q * 128;
    float* rq = (float*)(Pf + (size_t)Pn * 128);
    float* rp = rq + Q;

    float* oxor = (float*)d_out;
    float* ocos = oxor + (size_t)Q * (size_t)Pn;

    const int qgroups = Q / 16, pgroups = Pn / 16;
    conv_frag<<<qgroups, 256, 0, stream>>>(qe, Qf, qgroups);
    conv_frag<<<pgroups, 256, 0, stream>>>(pe, Pf, pgroups);
    prep_norms<<<(Q + Pn + 3) / 4, 256, 0, stream>>>(qe, pe, rq, rp, Q, Pn);

    const int nblocks = (Q / 16) * (Pn / PBLK);   // 256 * 8 = 2048
    fused_gemm<<<nblocks, 256, 0, stream>>>(Qf, Pf, qid, pid, rq, rp, oxor, ocos, Pn);
}

// Round 12
// 134.708 us; speedup vs baseline: 1.1887x; 1.0245x over previous
//
#include <hip/hip_runtime.h>
#include <stdint.h>

typedef __attribute__((ext_vector_type(8))) short bf16x8;
typedef __attribute__((ext_vector_type(4))) float f32x4;

__device__ __forceinline__ uint32_t f2bf(float f) {
    uint32_t u = __builtin_bit_cast(uint32_t, f);
    u += 0x7fffu + ((u >> 16) & 1u);   // RNE round to bf16
    return u >> 16;
}
__device__ __forceinline__ uint32_t pack2(float a, float b) {
    return f2bf(a) | (f2bf(b) << 16);
}

// Prep 1: reciprocal norms 1/max(||row||, eps).
__global__ __launch_bounds__(256) void prep_norms(const float* __restrict__ qe,
                                                  const float* __restrict__ pe,
                                                  float* __restrict__ rq,
                                                  float* __restrict__ rp,
                                                  int Q, int Pn) {
    int gw = (blockIdx.x * 256 + threadIdx.x) >> 6;  // one wave per row
    int lane = threadIdx.x & 63;
    if (gw >= Q + Pn) return;
    const float* src = (gw < Q) ? (qe + (size_t)gw * 128) : (pe + (size_t)(gw - Q) * 128);
    float2 v = *(const float2*)(src + lane * 2);
    float s = v.x * v.x + v.y * v.y;
#pragma unroll
    for (int off = 32; off > 0; off >>= 1) s += __shfl_down(s, off, 64);
    if (lane == 0) {
        float r = 1.0f / fmaxf(sqrtf(s), 1e-8f);
        if (gw < Q) rq[gw] = r; else rp[gw - Q] = r;
    }
}

// Prep 2: fp32 [rows][128] -> bf16 in MFMA-fragment order.
// Fragment (g = 16-row group, c = 32-wide k chunk): lane holds row g*16+(lane&15),
// k = c*32+(lane>>4)*8 .. +7. Flat halfword offset = ((g*4+c)*64 + lane)*8.
// A wave's fragment load in the GEMM = 64 contiguous 16B chunks = 1KB coalesced.
__global__ __launch_bounds__(256) void conv_frag(const float* __restrict__ src,
                                                 unsigned short* __restrict__ dst,
                                                 int ngroups) {
    int t = blockIdx.x * 256 + threadIdx.x;   // one thread per 8 outputs
    if (t >= ngroups * 256) return;
    int g = t >> 8, rem = t & 255;
    int c = rem >> 6, lane = rem & 63;
    int row = g * 16 + (lane & 15);
    int col = c * 32 + ((lane >> 4) << 3);
    const float* s = src + (size_t)row * 128 + col;
    float4 a0 = *(const float4*)s;
    float4 a1 = *(const float4*)(s + 4);
    uint4 pk = { pack2(a0.x, a0.y), pack2(a0.z, a0.w),
                 pack2(a1.x, a1.y), pack2(a1.z, a1.w) };
    *(uint4*)(dst + (size_t)t * 8) = pk;
}

#define PBLK 2048   // p extent per block

// Main v12 = R8 structure with QBLK=32: each wave computes TWO 16q groups per
// B-fragment read, halving L2/L3 B-read traffic (1.07GB -> 537MB) to unshare
// the cache fabric with the write stream. ZERO barriers, wave-private LDS
// transpose (stride 65), fused xor, NT stores.
__global__ __launch_bounds__(256, 4) void fused_gemm(
        const unsigned short* __restrict__ Qf, const unsigned short* __restrict__ Pf,
        const int* __restrict__ qid, const int* __restrict__ pid,
        const float* __restrict__ rq, const float* __restrict__ rp,
        float* __restrict__ oxor, float* __restrict__ ocos, int Pn) {
    __shared__ __align__(16) float scos[4][2][16 * 65];   // 33.3KB, per-wave slices

    // Bijective XCD chunking: each XCD owns a contiguous run of 32-row panels ->
    // contiguous ~64MB output slab per XCD; 128KB Qf slice stays L2-hot.
    const int nwg = gridDim.x;
    const int chunk = nwg >> 3;
    const int bid = blockIdx.x;
    const int wg = (bid & 7) * chunk + (bid >> 3);
    const int nPc = Pn / PBLK;
    const int qg2 = wg / nPc;          // 32-row q group
    const int pc = wg % nPc;
    const int pblock = pc * PBLK;

    const int t = threadIdx.x;
    const int lane = t & 63;
    const int w = t >> 6;
    const int lq = lane & 15;
    const int g4 = (lane >> 4) << 2;   // 0,4,8,12

    // A fragments: two 16-row groups, coalesced 1KB loads (32 VGPR)
    bf16x8 af[2][4];
#pragma unroll
    for (int j = 0; j < 2; ++j) {
        const unsigned short* abase = Qf + (size_t)(qg2 * 2 + j) * 2048 + lane * 8;
#pragma unroll
        for (int kk = 0; kk < 4; ++kk)
            af[j][kk] = *(const bf16x8*)(abase + kk * 512);
    }

    const int qrow_base = qg2 * 32;
    const float rqv0 = rq[qrow_base + lq];
    const float rqv1 = rq[qrow_base + 16 + lq];

    for (int fl = 0; fl < PBLK / 256; ++fl) {
        const int pw = pblock + fl * 256 + w * 64;   // this wave's 64p span
        // ---- compute: 4 fragments = 64p x 32q per B-read ----
#pragma unroll
        for (int f = 0; f < 4; ++f) {
            const int p0 = pw + f * 16;
            const unsigned short* bbase = Pf + (size_t)(p0 >> 4) * 2048 + (size_t)lane * 8;
            bf16x8 bfr[4];
#pragma unroll
            for (int kk = 0; kk < 4; ++kk)
                bfr[kk] = *(const bf16x8*)(bbase + kk * 512);
            f32x4 acc0 = {0.f, 0.f, 0.f, 0.f};
            f32x4 acc1 = {0.f, 0.f, 0.f, 0.f};
#pragma unroll
            for (int kk = 0; kk < 4; ++kk) {
                acc0 = __builtin_amdgcn_mfma_f32_16x16x32_bf16(bfr[kk], af[0][kk], acc0, 0, 0, 0);
                acc1 = __builtin_amdgcn_mfma_f32_16x16x32_bf16(bfr[kk], af[1][kk], acc1, 0, 0, 0);
            }
            // C layout: lane holds q = lane&15, p = p0 + (lane>>4)*4 + reg
            const float4 rpv = *(const float4*)(rp + p0 + g4);
            const int a0 = lq * 65 + f * 16 + g4;
            scos[w][0][a0 + 0] = acc0[0] * rqv0 * rpv.x;
            scos[w][0][a0 + 1] = acc0[1] * rqv0 * rpv.y;
            scos[w][0][a0 + 2] = acc0[2] * rqv0 * rpv.z;
            scos[w][0][a0 + 3] = acc0[3] * rqv0 * rpv.w;
            scos[w][1][a0 + 0] = acc1[0] * rqv1 * rpv.x;
            scos[w][1][a0 + 1] = acc1[1] * rqv1 * rpv.y;
            scos[w][1][a0 + 2] = acc1[2] * rqv1 * rpv.z;
            scos[w][1][a0 + 3] = acc1[3] * rqv1 * rpv.w;
        }
        // ---- flush (same wave, no barrier): 32 rows x 256B contiguous ----
        const int pvl = pid[pw + lane];
#pragma unroll
        for (int j = 0; j < 2; ++j) {
#pragma unroll
            for (int r = 0; r < 16; ++r) {
                const int row = j * 16 + r;
                const int qvr = qid[qrow_base + row];      // wave-uniform
                const size_t obase = (size_t)(qrow_base + row) * Pn + pw;
                float vc = scos[w][j][r * 65 + lane];
                float vx = (qvr == pvl) ? 1.f : 0.f;
                __builtin_nontemporal_store(vc, ocos + obase + lane);
                __builtin_nontemporal_store(vx, oxor + obase + lane);
            }
        }
    }
}

extern "C" void kernel_launch(void* const* d_in, const int* in_sizes, int n_in,
                              void* d_out, int out_size, void* d_ws, size_t ws_size,
                              hipStream_t stream) {
    const int*   qid = (const int*)d_in[0];
    const int*   pid = (const int*)d_in[1];
    const float* qe  = (const float*)d_in[2];
    const float* pe  = (const float*)d_in[3];
    const int Q  = in_sizes[0];   // 4096
    const int Pn = in_sizes[1];   // 16384

    // ws layout: Qf bf16 (Q*128), Pf bf16 (P*128), rq (Q), rp (P)  ~= 5.3 MB
    unsigned short* Qf = (unsigned short*)d_ws;
    unsigned short* Pf = Qf + (size_t)Q * 128;
    float* rq = (float*)(Pf + (size_t)Pn * 128);
    float* rp = rq + Q;

    float* oxor = (float*)d_out;
    float* ocos = oxor + (size_t)Q * (size_t)Pn;

    const int qgroups = Q / 16, pgroups = Pn / 16;
    conv_frag<<<qgroups, 256, 0, stream>>>(qe, Qf, qgroups);
    conv_frag<<<pgroups, 256, 0, stream>>>(pe, Pf, pgroups);
    prep_norms<<<(Q + Pn + 3) / 4, 256, 0, stream>>>(qe, pe, rq, rp, Q, Pn);

    const int nblocks = (Q / 32) * (Pn / PBLK);   // 128 * 8 = 1024
    fused_gemm<<<nblocks, 256, 0, stream>>>(Qf, Pf, qid, pid, rq, rp, oxor, ocos, Pn);
}

// Round 13
// 131.130 us; speedup vs baseline: 1.2212x; 1.0273x over previous
//
#include <hip/hip_runtime.h>
#include <stdint.h>

typedef __attribute__((ext_vector_type(8))) short bf16x8;
typedef __attribute__((ext_vector_type(4))) float f32x4;

__device__ __forceinline__ uint32_t f2bf(float f) {
    uint32_t u = __builtin_bit_cast(uint32_t, f);
    u += 0x7fffu + ((u >> 16) & 1u);   // RNE round to bf16
    return u >> 16;
}
__device__ __forceinline__ uint32_t pack2(float a, float b) {
    return f2bf(a) | (f2bf(b) << 16);
}

// Prep 1: reciprocal norms 1/max(||row||, eps).
__global__ __launch_bounds__(256) void prep_norms(const float* __restrict__ qe,
                                                  const float* __restrict__ pe,
                                                  float* __restrict__ rq,
                                                  float* __restrict__ rp,
                                                  int Q, int Pn) {
    int gw = (blockIdx.x * 256 + threadIdx.x) >> 6;  // one wave per row
    int lane = threadIdx.x & 63;
    if (gw >= Q + Pn) return;
    const float* src = (gw < Q) ? (qe + (size_t)gw * 128) : (pe + (size_t)(gw - Q) * 128);
    float2 v = *(const float2*)(src + lane * 2);
    float s = v.x * v.x + v.y * v.y;
#pragma unroll
    for (int off = 32; off > 0; off >>= 1) s += __shfl_down(s, off, 64);
    if (lane == 0) {
        float r = 1.0f / fmaxf(sqrtf(s), 1e-8f);
        if (gw < Q) rq[gw] = r; else rp[gw - Q] = r;
    }
}

// Prep 2: fp32 [rows][128] -> bf16 in MFMA-fragment order.
// Fragment (g = 16-row group, c = 32-wide k chunk): lane holds row g*16+(lane&15),
// k = c*32+(lane>>4)*8 .. +7. Flat halfword offset = ((g*4+c)*64 + lane)*8.
__global__ __launch_bounds__(256) void conv_frag(const float* __restrict__ src,
                                                 unsigned short* __restrict__ dst,
                                                 int ngroups) {
    int t = blockIdx.x * 256 + threadIdx.x;   // one thread per 8 outputs
    if (t >= ngroups * 256) return;
    int g = t >> 8, rem = t & 255;
    int c = rem >> 6, lane = rem & 63;
    int row = g * 16 + (lane & 15);
    int col = c * 32 + ((lane >> 4) << 3);
    const float* s = src + (size_t)row * 128 + col;
    float4 a0 = *(const float4*)s;
    float4 a1 = *(const float4*)(s + 4);
    uint4 pk = { pack2(a0.x, a0.y), pack2(a0.z, a0.w),
                 pack2(a1.x, a1.y), pack2(a1.z, a1.w) };
    *(uint4*)(dst + (size_t)t * 8) = pk;
}

// xor output as a PURE STREAMER, structurally identical to the harness fill:
// per thread: one L1-hot int4 load, one wave-uniform scalar, 4 compares, one
// 16B NT store; 64 lanes x 16B = 1KB/wave-instr, linear address walk.
// (Also the diagnostic: if THIS doesn't hit ~6.5 TB/s, nothing will.)
__global__ __launch_bounds__(256) void xor_stream(const int* __restrict__ qid,
                                                  const int* __restrict__ pid,
                                                  float* __restrict__ oxor,
                                                  int Pn_log2_div4) {
    const size_t T = (size_t)blockIdx.x * 256 + threadIdx.x;  // one per 4 outputs
    const int q  = (int)(T >> Pn_log2_div4);                  // wave-uniform
    const int pi = ((int)T & ((1 << Pn_log2_div4) - 1)) << 2;
    const int qv = qid[q];
    const int4 pv = *(const int4*)(pid + pi);
    f32x4 x = { pv.x == qv ? 1.f : 0.f, pv.y == qv ? 1.f : 0.f,
                pv.z == qv ? 1.f : 0.f, pv.w == qv ? 1.f : 0.f };
    __builtin_nontemporal_store(x, (f32x4*)(oxor + (T << 2)));
}

#define PBLK 2048   // p extent per block

// cos-only GEMM v13: R8 zero-barrier wave-private structure minus all xor work.
// Flush = 4 ds_read_b128 + 4 dwordx4 NT stores per round (16 rows x 256B).
// LDS row stride 68 words (16B-aligned rows, ~2-way banks).
__global__ __launch_bounds__(256, 4) void cos_gemm(
        const unsigned short* __restrict__ Qf, const unsigned short* __restrict__ Pf,
        const float* __restrict__ rq, const float* __restrict__ rp,
        float* __restrict__ ocos, int Pn) {
    __shared__ __align__(16) float scos[4][16][68];   // 17.4KB -> 4 blocks/CU

    // Bijective XCD chunking: XCD x owns a contiguous run of row-panels.
    const int nwg = gridDim.x;
    const int chunk = nwg >> 3;
    const int bid = blockIdx.x;
    const int wg = (bid & 7) * chunk + (bid >> 3);
    const int nPc = Pn / PBLK;
    const int qg = wg / nPc;           // 16-row q group
    const int pc = wg % nPc;
    const int pblock = pc * PBLK;

    const int t = threadIdx.x;
    const int lane = t & 63;
    const int w = t >> 6;
    const int lq = lane & 15;
    const int g4 = (lane >> 4) << 2;   // 0,4,8,12

    // A fragments: coalesced 1KB loads
    bf16x8 af[4];
    const unsigned short* abase = Qf + (size_t)qg * 2048 + lane * 8;
#pragma unroll
    for (int kk = 0; kk < 4; ++kk)
        af[kk] = *(const bf16x8*)(abase + kk * 512);

    const int qrow_base = qg * 16;
    const float rqv = rq[qrow_base + lq];

    // flush lane mapping: 4 store instrs cover 16 rows x 64p
    const int frow = lane >> 4;        // row within group of 4
    const int fcol = (lane & 15) * 4;  // 16B column

    for (int fl = 0; fl < PBLK / 256; ++fl) {
        const int pw = pblock + fl * 256 + w * 64;   // this wave's 64p span
        // ---- compute: 4 fragments = 64p ----
#pragma unroll
        for (int f = 0; f < 4; ++f) {
            const int p0 = pw + f * 16;
            const unsigned short* bbase = Pf + (size_t)(p0 >> 4) * 2048 + (size_t)lane * 8;
            bf16x8 bfr[4];
#pragma unroll
            for (int kk = 0; kk < 4; ++kk)
                bfr[kk] = *(const bf16x8*)(bbase + kk * 512);
            f32x4 acc = {0.f, 0.f, 0.f, 0.f};
#pragma unroll
            for (int kk = 0; kk < 4; ++kk)
                acc = __builtin_amdgcn_mfma_f32_16x16x32_bf16(bfr[kk], af[kk], acc, 0, 0, 0);
            // C layout: lane holds q = lane&15, p = p0 + (lane>>4)*4 + reg
            const float4 rpv = *(const float4*)(rp + p0 + g4);
            f32x4 c4 = { acc[0]*rqv*rpv.x, acc[1]*rqv*rpv.y,
                         acc[2]*rqv*rpv.z, acc[3]*rqv*rpv.w };
            *(f32x4*)&scos[w][lq][f * 16 + g4] = c4;
        }
        // ---- flush (same wave, no barrier): 4 instrs, 16 rows x 256B ----
#pragma unroll
        for (int rr = 0; rr < 4; ++rr) {
            const int row = rr * 4 + frow;
            f32x4 vc = *(const f32x4*)&scos[w][row][fcol];
            __builtin_nontemporal_store(vc,
                (f32x4*)(ocos + (size_t)(qrow_base + row) * Pn + pw + fcol));
        }
    }
}

extern "C" void kernel_launch(void* const* d_in, const int* in_sizes, int n_in,
                              void* d_out, int out_size, void* d_ws, size_t ws_size,
                              hipStream_t stream) {
    const int*   qid = (const int*)d_in[0];
    const int*   pid = (const int*)d_in[1];
    const float* qe  = (const float*)d_in[2];
    const float* pe  = (const float*)d_in[3];
    const int Q  = in_sizes[0];   // 4096
    const int Pn = in_sizes[1];   // 16384

    // ws layout: Qf bf16 (Q*128), Pf bf16 (P*128), rq (Q), rp (P)  ~= 5.3 MB
    unsigned short* Qf = (unsigned short*)d_ws;
    unsigned short* Pf = Qf + (size_t)Q * 128;
    float* rq = (float*)(Pf + (size_t)Pn * 128);
    float* rp = rq + Q;

    float* oxor = (float*)d_out;
    float* ocos = oxor + (size_t)Q * (size_t)Pn;

    const int qgroups = Q / 16, pgroups = Pn / 16;
    conv_frag<<<qgroups, 256, 0, stream>>>(qe, Qf, qgroups);
    conv_frag<<<pgroups, 256, 0, stream>>>(pe, Pf, pgroups);
    prep_norms<<<(Q + Pn + 3) / 4, 256, 0, stream>>>(qe, pe, rq, rp, Q, Pn);

    // Pn/4 = 4096 = 2^12
    int lg = 0; while ((1 << lg) != Pn / 4) ++lg;
    const int nxb = (int)(((size_t)Q * Pn / 4) / 256);   // 65536
    xor_stream<<<nxb, 256, 0, stream>>>(qid, pid, oxor, lg);

    const int nblocks = (Q / 16) * (Pn / PBLK);   // 2048
    cos_gemm<<<nblocks, 256, 0, stream>>>(Qf, Pf, rq, rp, ocos, Pn);
}

// Round 14
// 127.544 us; speedup vs baseline: 1.2555x; 1.0281x over previous
//
#include <hip/hip_runtime.h>
#include <stdint.h>

typedef __attribute__((ext_vector_type(8))) short bf16x8;
typedef __attribute__((ext_vector_type(4))) float f32x4;

__device__ __forceinline__ uint32_t f2bf(float f) {
    uint32_t u = __builtin_bit_cast(uint32_t, f);
    u += 0x7fffu + ((u >> 16) & 1u);   // RNE round to bf16
    return u >> 16;
}
__device__ __forceinline__ uint32_t pack2(float a, float b) {
    return f2bf(a) | (f2bf(b) << 16);
}

// Fused prep: fp32 [rows][128] -> bf16 fragment order AND reciprocal norms,
// one block per 16-row group (qe groups first, then pe groups).
// Thread t (rem in [0,256)): c=rem>>6, lane=rem&63, row=(lane&15), holds
// k = c*32+(lane>>4)*8 .. +7 of that row -> same data feeds pack AND ssq.
__global__ __launch_bounds__(256) void prep_all(const float* __restrict__ qe,
                                                const float* __restrict__ pe,
                                                unsigned short* __restrict__ Qf,
                                                unsigned short* __restrict__ Pf,
                                                float* __restrict__ rq,
                                                float* __restrict__ rp,
                                                int qgroups) {
    __shared__ float part[16][17];
    const int gi = blockIdx.x;
    const int rem = threadIdx.x;
    const bool isQ = gi < qgroups;
    const int g = isQ ? gi : gi - qgroups;          // local group index
    const float* src = isQ ? qe : pe;
    unsigned short* dst = isQ ? Qf : Pf;

    const int c = rem >> 6, lane = rem & 63;
    const int rowl = lane & 15;
    const int hi = lane >> 4;
    const int row = g * 16 + rowl;
    const int col = c * 32 + hi * 8;
    const float* s = src + (size_t)row * 128 + col;
    float4 a0 = *(const float4*)s;
    float4 a1 = *(const float4*)(s + 4);
    uint4 pk = { pack2(a0.x, a0.y), pack2(a0.z, a0.w),
                 pack2(a1.x, a1.y), pack2(a1.z, a1.w) };
    *(uint4*)(dst + ((size_t)g * 256 + rem) * 8) = pk;

    float ssq = a0.x*a0.x + a0.y*a0.y + a0.z*a0.z + a0.w*a0.w
              + a1.x*a1.x + a1.y*a1.y + a1.z*a1.z + a1.w*a1.w;
    part[rowl][c * 4 + hi] = ssq;
    __syncthreads();
    if (rem < 16) {
        float s16 = 0.f;
#pragma unroll
        for (int j = 0; j < 16; ++j) s16 += part[rem][j];
        float r = 1.0f / fmaxf(sqrtf(s16), 1e-8f);
        (isQ ? rq : rp)[g * 16 + rem] = r;
    }
}

// xor streamer: grid-strided (2048 blocks -> no CP dispatch-rate overhead),
// linear 1KB/wave-instr NT stores, pid int4 loads L2-hot.
__global__ __launch_bounds__(256) void xor_stream(const int* __restrict__ qid,
                                                  const int* __restrict__ pid,
                                                  float* __restrict__ oxor,
                                                  int total4, int pmask_log2) {
    const int stride = gridDim.x * 256;
    int idx = blockIdx.x * 256 + threadIdx.x;
    const int pmask = (1 << pmask_log2) - 1;
    for (; idx < total4; idx += stride) {
        const int q = idx >> pmask_log2;
        const int pi = (idx & pmask) << 2;
        const int qv = qid[q];
        const int4 pv = *(const int4*)(pid + pi);
        f32x4 x = { pv.x == qv ? 1.f : 0.f, pv.y == qv ? 1.f : 0.f,
                    pv.z == qv ? 1.f : 0.f, pv.w == qv ? 1.f : 0.f };
        __builtin_nontemporal_store(x, (f32x4*)(oxor + ((size_t)idx << 2)));
    }
}

#define PBLK 2048   // p extent per block

// cos-only GEMM v14: R8 zero-barrier wave-private structure; flush reverted to
// R8-style: 16 x (64 lanes x 4B = 256B row-contiguous) NT stores per round.
__global__ __launch_bounds__(256, 4) void cos_gemm(
        const unsigned short* __restrict__ Qf, const unsigned short* __restrict__ Pf,
        const float* __restrict__ rq, const float* __restrict__ rp,
        float* __restrict__ ocos, int Pn) {
    __shared__ __align__(16) float scos[4][16][68];   // 17.4KB -> 4 blocks/CU

    // Bijective XCD chunking: XCD x owns a contiguous run of row-panels.
    const int nwg = gridDim.x;
    const int chunk = nwg >> 3;
    const int bid = blockIdx.x;
    const int wg = (bid & 7) * chunk + (bid >> 3);
    const int nPc = Pn / PBLK;
    const int qg = wg / nPc;           // 16-row q group
    const int pc = wg % nPc;
    const int pblock = pc * PBLK;

    const int t = threadIdx.x;
    const int lane = t & 63;
    const int w = t >> 6;
    const int lq = lane & 15;
    const int g4 = (lane >> 4) << 2;   // 0,4,8,12

    // A fragments: coalesced 1KB loads
    bf16x8 af[4];
    const unsigned short* abase = Qf + (size_t)qg * 2048 + lane * 8;
#pragma unroll
    for (int kk = 0; kk < 4; ++kk)
        af[kk] = *(const bf16x8*)(abase + kk * 512);

    const int qrow_base = qg * 16;
    const float rqv = rq[qrow_base + lq];

    for (int fl = 0; fl < PBLK / 256; ++fl) {
        const int pw = pblock + fl * 256 + w * 64;   // this wave's 64p span
        // ---- compute: 4 fragments = 64p ----
#pragma unroll
        for (int f = 0; f < 4; ++f) {
            const int p0 = pw + f * 16;
            const unsigned short* bbase = Pf + (size_t)(p0 >> 4) * 2048 + (size_t)lane * 8;
            bf16x8 bfr[4];
#pragma unroll
            for (int kk = 0; kk < 4; ++kk)
                bfr[kk] = *(const bf16x8*)(bbase + kk * 512);
            f32x4 acc = {0.f, 0.f, 0.f, 0.f};
#pragma unroll
            for (int kk = 0; kk < 4; ++kk)
                acc = __builtin_amdgcn_mfma_f32_16x16x32_bf16(bfr[kk], af[kk], acc, 0, 0, 0);
            // C layout: lane holds q = lane&15, p = p0 + (lane>>4)*4 + reg
            const float4 rpv = *(const float4*)(rp + p0 + g4);
            f32x4 c4 = { acc[0]*rqv*rpv.x, acc[1]*rqv*rpv.y,
                         acc[2]*rqv*rpv.z, acc[3]*rqv*rpv.w };
            *(f32x4*)&scos[w][lq][f * 16 + g4] = c4;
        }
        // ---- flush (same wave, no barrier): 16 x 256B row-contiguous ----
#pragma unroll
        for (int r = 0; r < 16; ++r) {
            float vc = scos[w][r][lane];
            __builtin_nontemporal_store(vc,
                ocos + (size_t)(qrow_base + r) * Pn + pw + lane);
        }
    }
}

extern "C" void kernel_launch(void* const* d_in, const int* in_sizes, int n_in,
                              void* d_out, int out_size, void* d_ws, size_t ws_size,
                              hipStream_t stream) {
    const int*   qid = (const int*)d_in[0];
    const int*   pid = (const int*)d_in[1];
    const float* qe  = (const float*)d_in[2];
    const float* pe  = (const float*)d_in[3];
    const int Q  = in_sizes[0];   // 4096
    const int Pn = in_sizes[1];   // 16384

    // ws layout: Qf bf16 (Q*128), Pf bf16 (P*128), rq (Q), rp (P)  ~= 5.3 MB
    unsigned short* Qf = (unsigned short*)d_ws;
    unsigned short* Pf = Qf + (size_t)Q * 128;
    float* rq = (float*)(Pf + (size_t)Pn * 128);
    float* rp = rq + Q;

    float* oxor = (float*)d_out;
    float* ocos = oxor + (size_t)Q * (size_t)Pn;

    const int qgroups = Q / 16, pgroups = Pn / 16;
    prep_all<<<qgroups + pgroups, 256, 0, stream>>>(qe, pe, Qf, Pf, rq, rp, qgroups);

    int lg = 0; while ((1 << lg) != Pn / 4) ++lg;          // Pn/4 = 4096 -> 12
    const int total4 = (int)((size_t)Q * Pn / 4);          // 16.7M 16B-stores
    xor_stream<<<2048, 256, 0, stream>>>(qid, pid, oxor, total4, lg);

    const int nblocks = (Q / 16) * (Pn / PBLK);            // 2048
    cos_gemm<<<nblocks, 256, 0, stream>>>(Qf, Pf, rq, rp, ocos, Pn);
}